// Round 19
// baseline (172.354 us; speedup 1.0000x reference)
//
#include <hip/hip_runtime.h>
#include <math.h>

constexpr int FEAT = 128;   // DIN == DH == 128

typedef __attribute__((ext_vector_type(8))) short short8v;   // 8 bf16 raw / 16 B
typedef __attribute__((ext_vector_type(4))) float f32x4;
typedef __attribute__((ext_vector_type(2))) float f32x2;
typedef __attribute__((ext_vector_type(4))) int   int4v;

// ---- fp32 -> bf16 (RNE) / fp8 helpers ----
__device__ inline unsigned short f2bf(float f) {
    unsigned int u = __float_as_uint(f);
    u += 0x7fffu + ((u >> 16) & 1u);
    return (unsigned short)(u >> 16);
}
__device__ inline float bf2f(unsigned short h) {
    return __uint_as_float(((unsigned int)h) << 16);
}
__device__ inline unsigned char f2fp8(float f) {
    int r = __builtin_amdgcn_cvt_pk_fp8_f32(f, 0.f, 0, false);
    return (unsigned char)(r & 0xff);
}

// ================= fused CSR bucket phase 1 + weight/x prep =================
__global__ __launch_bounds__(1024) void bucket_prep_kernel(
    const int* __restrict__ src, const int* __restrict__ dst,
    unsigned int* __restrict__ chunkdata, int* __restrict__ table,
    int E, int nbk, int nch,
    const float* __restrict__ W1l, const float* __restrict__ W1r,
    const float* __restrict__ W2l, const float* __restrict__ W2r,
    const float* __restrict__ W3l, const float* __restrict__ W3r,
    unsigned short* __restrict__ WTh1, unsigned short* __restrict__ WTl1,
    unsigned short* __restrict__ WTh2, unsigned short* __restrict__ WTl2,
    unsigned short* __restrict__ WTh3, unsigned short* __restrict__ WTl3,
    const float* __restrict__ x, unsigned short* __restrict__ xbf,
    unsigned char* __restrict__ xf8, int total4)
{
    __shared__ int cnt[128];
    __shared__ int part[128];
    __shared__ int sbase[128];
    __shared__ unsigned int sbuf[8192];
    const int t = threadIdx.x;
    const int blk = blockIdx.x;

    if (blk >= nch) {
        int b = blk - nch;
        if (b < 80) {
            const float *Wl, *Wr;
            unsigned short *WTh, *WTl;
            int dout, idx;
            if (b < 32)      { Wl = W1l; Wr = W1r; WTh = WTh1; WTl = WTl1; dout = 128; idx = b * 1024 + t; }
            else if (b < 64) { Wl = W2l; Wr = W2r; WTh = WTh2; WTl = WTl2; dout = 128; idx = (b - 32) * 1024 + t; }
            else             { Wl = W3l; Wr = W3r; WTh = WTh3; WTl = WTl3; dout = 64;  idx = (b - 64) * 1024 + t; }
            if (idx < dout * 256) {
                int c = idx >> 8;
                int k = idx & 255;
                float v = (k < 128) ? Wl[(size_t)k * dout + c] : Wr[(size_t)(k - 128) * dout + c];
                unsigned short h = f2bf(v);
                WTh[(size_t)c * 256 + k] = h;
                WTl[(size_t)c * 256 + k] = f2bf(v - bf2f(h));
            }
        } else {
            int i = (b - 80) * 1024 + t;
            if (i < total4) {
                float4 v = *(const float4*)(x + (size_t)i * 4);
                ushort4 h;
                h.x = f2bf(v.x); h.y = f2bf(v.y); h.z = f2bf(v.z); h.w = f2bf(v.w);
                *(ushort4*)(xbf + (size_t)i * 4) = h;
                uchar4 c;
                c.x = f2fp8(v.x); c.y = f2fp8(v.y); c.z = f2fp8(v.z); c.w = f2fp8(v.w);
                *(uchar4*)(xf8 + (size_t)i * 4) = c;
            }
        }
        return;
    }

    const int c = blk;
    const int e0 = c * 8192;

    if (t < 128) cnt[t] = 0;
    __syncthreads();

    unsigned int word[8];
    int bkt[8], rnk[8];
    #pragma unroll
    for (int it = 0; it < 2; ++it) {
        int e = e0 + it * 4096 + t * 4;
        int4 d4 = make_int4(0, 0, 0, 0), s4 = d4;
        if (e + 3 < E) {
            d4 = *(const int4*)(dst + e);
            s4 = *(const int4*)(src + e);
        } else {
            if (e + 0 < E) { d4.x = dst[e + 0]; s4.x = src[e + 0]; } else d4.x = -1;
            if (e + 1 < E) { d4.y = dst[e + 1]; s4.y = src[e + 1]; } else d4.y = -1;
            if (e + 2 < E) { d4.z = dst[e + 2]; s4.z = src[e + 2]; } else d4.z = -1;
            if (e + 3 < E) { d4.w = dst[e + 3]; s4.w = src[e + 3]; } else d4.w = -1;
        }
        int dd[4] = {d4.x, d4.y, d4.z, d4.w};
        int ss[4] = {s4.x, s4.y, s4.z, s4.w};
        #pragma unroll
        for (int q = 0; q < 4; ++q) {
            int i = it * 4 + q;
            int d = dd[q];
            if (d >= 0) {
                bkt[i]  = d >> 9;
                rnk[i]  = atomicAdd(&cnt[bkt[i]], 1);
                word[i] = (unsigned int)ss[q] | ((unsigned int)(d & 511) << 16);
            } else bkt[i] = -1;
        }
    }
    __syncthreads();

    if (t < 128) part[t] = cnt[t];
    __syncthreads();
    for (int s = 1; s < 128; s <<= 1) {
        int v = (t >= s && t < 128) ? part[t - s] : 0;
        __syncthreads();
        if (t < 128) part[t] += v;
        __syncthreads();
    }
    if (t < 128) sbase[t] = part[t] - cnt[t];
    __syncthreads();

    if (t <= nbk) table[(size_t)c * (nbk + 1) + t] = sbase[t];

    #pragma unroll
    for (int i = 0; i < 8; ++i)
        if (bkt[i] >= 0) sbuf[sbase[bkt[i]] + rnk[i]] = word[i];
    __syncthreads();

    const int total = part[127];
    for (int i = t; i < total; i += 1024)
        chunkdata[(size_t)c * 8192 + i] = sbuf[i];
}

// Phase 2: per-bucket two-pass counting sort -> offs/invd + ushort eidx flush.
constexpr int P2CAP = 10240;
__global__ __launch_bounds__(1024) void fillsort_kernel(const unsigned int* __restrict__ chunkdata,
                                                        const int* __restrict__ table,
                                                        int* __restrict__ offs,
                                                        float* __restrict__ invd,
                                                        unsigned short* __restrict__ eidx,
                                                        int n, int nch, int nbk, int E) {
    __shared__ int cnt[512];
    __shared__ int lcur[512];
    __shared__ int part[512];
    __shared__ int redb[16];
    __shared__ int lbuf[P2CAP];
    const int b  = blockIdx.x;
    const int t  = threadIdx.x;
    const int lo = b << 9;

    int partial = 0;
    for (int c = t; c < nch; c += 1024) partial += table[(size_t)c * (nbk + 1) + b];
    #pragma unroll
    for (int off = 32; off > 0; off >>= 1) partial += __shfl_down(partial, off, 64);
    if ((t & 63) == 0) redb[t >> 6] = partial;
    for (int i = t; i < 512; i += 1024) cnt[i] = 0;
    __syncthreads();
    int base = 0;
    #pragma unroll
    for (int i = 0; i < 16; ++i) base += redb[i];

    const int w    = t >> 6;
    const int lane = t & 63;
    for (int c = w; c < nch; c += 16) {
        int o0 = table[(size_t)c * (nbk + 1) + b];
        int o1 = table[(size_t)c * (nbk + 1) + b + 1];
        for (int i = o0 + lane; i < o1; i += 64)
            atomicAdd(&cnt[(chunkdata[(size_t)c * 8192 + i] >> 16) & 511], 1);
    }
    __syncthreads();

    int v = (t < 512) ? cnt[t] : 0;
    if (t < 512) part[t] = v;
    __syncthreads();
    for (int s = 1; s < 512; s <<= 1) {
        int u = (t >= s && t < 512) ? part[t - s] : 0;
        __syncthreads();
        if (t < 512) part[t] += u;
        __syncthreads();
    }
    const int total = part[511];
    if (t < 512) {
        int ex = part[t] - v;
        lcur[t] = ex;
        int idx = lo + t;
        if (idx < n) {
            offs[idx] = base + ex;
            invd[idx] = 1.0f / fmaxf((float)v, 1.0f);
        }
    }
    if (b == nbk - 1 && t == 0) offs[n] = E;
    __syncthreads();

    for (int c = w; c < nch; c += 16) {
        int o0 = table[(size_t)c * (nbk + 1) + b];
        int o1 = table[(size_t)c * (nbk + 1) + b + 1];
        for (int i = o0 + lane; i < o1; i += 64) {
            unsigned int wd = chunkdata[(size_t)c * 8192 + i];
            int s = wd & 0xffff;
            int p = atomicAdd(&lcur[(wd >> 16) & 511], 1);
            if (p < P2CAP) lbuf[p] = s;
            else           eidx[base + p] = (unsigned short)s;
        }
    }
    __syncthreads();

    const int m = min(total, P2CAP);
    for (int i = t; i < m; i += 1024) eidx[base + i] = (unsigned short)lbuf[i];
}

// ================= CSR build fallback (N > 65536) =================
__global__ void deg_kernel(const int* __restrict__ dst, int* __restrict__ degi, int E) {
    int e = blockIdx.x * 256 + threadIdx.x;
    if (e < E) atomicAdd(&degi[__builtin_nontemporal_load(dst + e)], 1);
}
__global__ __launch_bounds__(256) void blockred_kernel(const int* __restrict__ deg,
                                                       int* __restrict__ bsum, int n) {
    __shared__ int red[256];
    int base = blockIdx.x * 1024 + threadIdx.x * 4;
    int s = 0;
    if (base + 3 < n) {
        int4 v = *(const int4*)(deg + base);
        s = v.x + v.y + v.z + v.w;
    } else {
        for (int i = 0; i < 4; ++i) if (base + i < n) s += deg[base + i];
    }
    red[threadIdx.x] = s;
    __syncthreads();
    for (int st = 128; st > 0; st >>= 1) {
        if (threadIdx.x < st) red[threadIdx.x] += red[threadIdx.x + st];
        __syncthreads();
    }
    if (threadIdx.x == 0) bsum[blockIdx.x] = red[0];
}
__global__ __launch_bounds__(256) void scanb_kernel(const int* __restrict__ bsum,
                                                    int* __restrict__ bpre, int nb) {
    __shared__ int part[256];
    int t = threadIdx.x;
    int v = (t < nb) ? bsum[t] : 0;
    part[t] = v;
    __syncthreads();
    for (int s = 1; s < 256; s <<= 1) {
        int u = (t >= s) ? part[t - s] : 0;
        __syncthreads();
        part[t] += u;
        __syncthreads();
    }
    if (t < nb) bpre[t] = part[t] - v;
}
__global__ __launch_bounds__(256) void scanfill_kernel(const int* __restrict__ deg,
                                                       const int* __restrict__ bpre,
                                                       int* __restrict__ offs,
                                                       int* __restrict__ cur,
                                                       float* __restrict__ invd,
                                                       int n, int E) {
    __shared__ int part[256];
    int t = threadIdx.x;
    int base = blockIdx.x * 1024 + t * 4;
    int d[4];
    int s = 0;
    #pragma unroll
    for (int i = 0; i < 4; ++i) {
        d[i] = (base + i < n) ? deg[base + i] : 0;
        s += d[i];
    }
    part[t] = s;
    __syncthreads();
    for (int st = 1; st < 256; st <<= 1) {
        int u = (t >= st) ? part[t - st] : 0;
        __syncthreads();
        part[t] += u;
        __syncthreads();
    }
    int pre = bpre[blockIdx.x] + part[t] - s;
    #pragma unroll
    for (int i = 0; i < 4; ++i) {
        int idx = base + i;
        if (idx < n) {
            offs[idx] = pre;
            cur[idx]  = pre;
            invd[idx] = 1.0f / fmaxf((float)d[i], 1.0f);
            pre += d[i];
        }
    }
    if (blockIdx.x == 0 && t == 0) offs[n] = E;
}
constexpr int FCH = 4096;
__global__ __launch_bounds__(256) void fill_xcd_kernel(const int* __restrict__ src,
                                                       const int* __restrict__ dst,
                                                       int* __restrict__ cur,
                                                       int* __restrict__ eidx,
                                                       int E, int rsize) {
    const int p     = blockIdx.x & 7;
    const int chunk = blockIdx.x >> 3;
    const int lo = p * rsize;
    const int hi = lo + rsize;
    #pragma unroll
    for (int it = 0; it < 4; ++it) {
        int e = chunk * FCH + (it * 256 + threadIdx.x) * 4;
        if (e + 3 < E) {
            int4v d4 = __builtin_nontemporal_load((const int4v*)(dst + e));
            #pragma unroll
            for (int q = 0; q < 4; ++q) {
                int d = d4[q];
                if (d >= lo && d < hi) {
                    int pos = atomicAdd(&cur[d], 1);
                    eidx[pos] = __builtin_nontemporal_load(src + e + q);
                }
            }
        } else {
            for (int q = 0; e + q < E && q < 4; ++q) {
                int d = dst[e + q];
                if (d >= lo && d < hi) {
                    int pos = atomicAdd(&cur[d], 1);
                    eidx[pos] = src[e + q];
                }
            }
        }
    }
}
__global__ __launch_bounds__(256) void prep_kernel(
    const float* __restrict__ W1l, const float* __restrict__ W1r,
    const float* __restrict__ W2l, const float* __restrict__ W2r,
    const float* __restrict__ W3l, const float* __restrict__ W3r,
    unsigned short* __restrict__ WTh1, unsigned short* __restrict__ WTl1,
    unsigned short* __restrict__ WTh2, unsigned short* __restrict__ WTl2,
    unsigned short* __restrict__ WTh3, unsigned short* __restrict__ WTl3,
    const float* __restrict__ x, unsigned short* __restrict__ xbf,
    unsigned char* __restrict__ xf8, int total4)
{
    const int b = blockIdx.x;
    if (b < 320) {
        const float *Wl, *Wr;
        unsigned short *WTh, *WTl;
        int dout, idx;
        if (b < 128)      { Wl = W1l; Wr = W1r; WTh = WTh1; WTl = WTl1; dout = 128; idx = b * 256 + threadIdx.x; }
        else if (b < 256) { Wl = W2l; Wr = W2r; WTh = WTh2; WTl = WTl2; dout = 128; idx = (b - 128) * 256 + threadIdx.x; }
        else              { Wl = W3l; Wr = W3r; WTh = WTh3; WTl = WTl3; dout = 64;  idx = (b - 256) * 256 + threadIdx.x; }
        if (idx < dout * 256) {
            int c = idx >> 8;
            int k = idx & 255;
            float v = (k < 128) ? Wl[(size_t)k * dout + c] : Wr[(size_t)(k - 128) * dout + c];
            unsigned short h = f2bf(v);
            WTh[(size_t)c * 256 + k] = h;
            WTl[(size_t)c * 256 + k] = f2bf(v - bf2f(h));
        }
    } else {
        int i = (b - 320) * 256 + threadIdx.x;
        if (i < total4) {
            float4 v = *(const float4*)(x + (size_t)i * 4);
            ushort4 h;
            h.x = f2bf(v.x); h.y = f2bf(v.y); h.z = f2bf(v.z); h.w = f2bf(v.w);
            *(ushort4*)(xbf + (size_t)i * 4) = h;
            uchar4 c;
            c.x = f2fp8(v.x); c.y = f2fp8(v.y); c.z = f2fp8(v.z); c.w = f2fp8(v.w);
            *(uchar4*)(xf8 + (size_t)i * 4) = c;
        }
    }
}

// ================= gather mean from fp8 feats -> bf16 mean =================
// 8-lane groups x 16-B loads: one wave VMEM instruction covers 8 edge rows
// (vs 4 with 8-B loads) -> half the scattered-VMEM issue count. Depth-2
// unroll keeps 16 rows in flight. Indices prefetched once (coalesced) into
// the wave's private LDS slice (exec-mask-safe; round-17 lesson: no shfl in
// divergent loops). Cross-lane reduce only after loop reconvergence.
template <typename IT>
__global__ __launch_bounds__(256) void gather_f8_kernel(const unsigned char* __restrict__ featf8,
                                                        const int* __restrict__ offs,
                                                        const IT* __restrict__ eidx,
                                                        const float* __restrict__ invd,
                                                        unsigned short* __restrict__ aggbf, int n) {
    __shared__ int sidx[4][64];
    const int widx = threadIdx.x >> 6;
    int node = blockIdx.x * 4 + widx;
    if (node >= n) return;
    const int l    = threadIdx.x & 63;
    const int grp  = l >> 3;          // 8 groups of 8 lanes
    const int li   = l & 7;
    const int c16  = li * 16;         // 16 fp8 features per lane
    const int beg = offs[node], end = offs[node + 1];
    const int deg = end - beg;

    // one coalesced index prefetch into this wave's private LDS slice
    if (l < deg) sidx[widx][l] = (int)eidx[beg + l];

    float acc[16];
    #pragma unroll
    for (int q = 0; q < 16; ++q) acc[q] = 0.f;

    const int m = min(deg, 64);
    int k = grp;
    // depth-2: 16 rows in flight per wave, 8 rows per VMEM instruction
    for (; k + 8 < m; k += 16) {
        int s0 = sidx[widx][k];
        int s1 = sidx[widx][k + 8];
        uint4 v0 = *(const uint4*)(featf8 + (size_t)s0 * FEAT + c16);
        uint4 v1 = *(const uint4*)(featf8 + (size_t)s1 * FEAT + c16);
        f32x2 p;
        p = __builtin_amdgcn_cvt_pk_f32_fp8(v0.x, false); acc[0]  += p.x; acc[1]  += p.y;
        p = __builtin_amdgcn_cvt_pk_f32_fp8(v0.x, true);  acc[2]  += p.x; acc[3]  += p.y;
        p = __builtin_amdgcn_cvt_pk_f32_fp8(v0.y, false); acc[4]  += p.x; acc[5]  += p.y;
        p = __builtin_amdgcn_cvt_pk_f32_fp8(v0.y, true);  acc[6]  += p.x; acc[7]  += p.y;
        p = __builtin_amdgcn_cvt_pk_f32_fp8(v0.z, false); acc[8]  += p.x; acc[9]  += p.y;
        p = __builtin_amdgcn_cvt_pk_f32_fp8(v0.z, true);  acc[10] += p.x; acc[11] += p.y;
        p = __builtin_amdgcn_cvt_pk_f32_fp8(v0.w, false); acc[12] += p.x; acc[13] += p.y;
        p = __builtin_amdgcn_cvt_pk_f32_fp8(v0.w, true);  acc[14] += p.x; acc[15] += p.y;
        p = __builtin_amdgcn_cvt_pk_f32_fp8(v1.x, false); acc[0]  += p.x; acc[1]  += p.y;
        p = __builtin_amdgcn_cvt_pk_f32_fp8(v1.x, true);  acc[2]  += p.x; acc[3]  += p.y;
        p = __builtin_amdgcn_cvt_pk_f32_fp8(v1.y, false); acc[4]  += p.x; acc[5]  += p.y;
        p = __builtin_amdgcn_cvt_pk_f32_fp8(v1.y, true);  acc[6]  += p.x; acc[7]  += p.y;
        p = __builtin_amdgcn_cvt_pk_f32_fp8(v1.z, false); acc[8]  += p.x; acc[9]  += p.y;
        p = __builtin_amdgcn_cvt_pk_f32_fp8(v1.z, true);  acc[10] += p.x; acc[11] += p.y;
        p = __builtin_amdgcn_cvt_pk_f32_fp8(v1.w, false); acc[12] += p.x; acc[13] += p.y;
        p = __builtin_amdgcn_cvt_pk_f32_fp8(v1.w, true);  acc[14] += p.x; acc[15] += p.y;
    }
    for (; k < m; k += 8) {
        int s0 = sidx[widx][k];
        uint4 v0 = *(const uint4*)(featf8 + (size_t)s0 * FEAT + c16);
        f32x2 p;
        p = __builtin_amdgcn_cvt_pk_f32_fp8(v0.x, false); acc[0]  += p.x; acc[1]  += p.y;
        p = __builtin_amdgcn_cvt_pk_f32_fp8(v0.x, true);  acc[2]  += p.x; acc[3]  += p.y;
        p = __builtin_amdgcn_cvt_pk_f32_fp8(v0.y, false); acc[4]  += p.x; acc[5]  += p.y;
        p = __builtin_amdgcn_cvt_pk_f32_fp8(v0.y, true);  acc[6]  += p.x; acc[7]  += p.y;
        p = __builtin_amdgcn_cvt_pk_f32_fp8(v0.z, false); acc[8]  += p.x; acc[9]  += p.y;
        p = __builtin_amdgcn_cvt_pk_f32_fp8(v0.z, true);  acc[10] += p.x; acc[11] += p.y;
        p = __builtin_amdgcn_cvt_pk_f32_fp8(v0.w, false); acc[12] += p.x; acc[13] += p.y;
        p = __builtin_amdgcn_cvt_pk_f32_fp8(v0.w, true);  acc[14] += p.x; acc[15] += p.y;
    }
    // rare tail: deg > 64 (direct loads, still correct)
    for (int j = beg + 64 + grp; j < end; j += 8) {
        int s0 = (int)eidx[j];
        uint4 v0 = *(const uint4*)(featf8 + (size_t)s0 * FEAT + c16);
        f32x2 p;
        p = __builtin_amdgcn_cvt_pk_f32_fp8(v0.x, false); acc[0]  += p.x; acc[1]  += p.y;
        p = __builtin_amdgcn_cvt_pk_f32_fp8(v0.x, true);  acc[2]  += p.x; acc[3]  += p.y;
        p = __builtin_amdgcn_cvt_pk_f32_fp8(v0.y, false); acc[4]  += p.x; acc[5]  += p.y;
        p = __builtin_amdgcn_cvt_pk_f32_fp8(v0.y, true);  acc[6]  += p.x; acc[7]  += p.y;
        p = __builtin_amdgcn_cvt_pk_f32_fp8(v0.z, false); acc[8]  += p.x; acc[9]  += p.y;
        p = __builtin_amdgcn_cvt_pk_f32_fp8(v0.z, true);  acc[10] += p.x; acc[11] += p.y;
        p = __builtin_amdgcn_cvt_pk_f32_fp8(v0.w, false); acc[12] += p.x; acc[13] += p.y;
        p = __builtin_amdgcn_cvt_pk_f32_fp8(v0.w, true);  acc[14] += p.x; acc[15] += p.y;
    }

    // reduce across the 8 groups (wave-convergent point)
    #pragma unroll
    for (int off = 8; off < 64; off <<= 1)
        #pragma unroll
        for (int q = 0; q < 16; ++q)
            acc[q] += __shfl_xor(acc[q], off, 64);

    if (grp == 0) {
        float sc = invd[node];
        unsigned short o[16];
        #pragma unroll
        for (int q = 0; q < 16; ++q) o[q] = f2bf(acc[q] * sc);
        unsigned short* dstp = aggbf + (size_t)node * FEAT + c16;
        *(short8v*)dstp       = *(short8v*)&o[0];
        *(short8v*)(dstp + 8) = *(short8v*)&o[8];
    }
}

// ================= MFMA dense, LDS-resident B (ALL DOUT cols) =================
template <int DOUT, bool WBF, bool WF8, bool LSM>
__global__ __launch_bounds__(1024, 4) void dense_mfma(
    const unsigned short* __restrict__ meanbf, const unsigned short* __restrict__ xinbf,
    const unsigned short* __restrict__ WTh, const unsigned short* __restrict__ WTl,
    const float* __restrict__ bias,
    float* outf, unsigned short* outbf, unsigned char* outf8, int n)
{
    constexpr int NCT = DOUT / 16;
    __shared__ unsigned short Bh[DOUT * 256];
    __shared__ unsigned short Bl[DOUT * 256];
    const int tid = threadIdx.x;

    #pragma unroll
    for (int it = 0; it < DOUT / 32; ++it) {
        int o  = (tid + it * 1024) * 8;
        int cl = o >> 8;
        int k  = o & 255;
        size_t gsrc = (size_t)cl * 256 + k;
        int db = (o * 2) ^ ((cl & 7) << 4);
        *(short8v*)((char*)Bh + db) = *(const short8v*)(WTh + gsrc);
        *(short8v*)((char*)Bl + db) = *(const short8v*)(WTl + gsrc);
    }
    __syncthreads();

    const int l    = tid & 63;
    const int w    = tid >> 6;
    const int l15  = l & 15;
    const int lg   = l >> 4;
    const int row0 = blockIdx.x * 256 + w * 16;
    if (row0 >= n) return;
    const int g = row0 + l15;

    f32x4 acc[NCT];
    #pragma unroll
    for (int ct = 0; ct < NCT; ++ct) acc[ct] = (f32x4){0.f, 0.f, 0.f, 0.f};

    #pragma unroll
    for (int ch = 0; ch < 8; ++ch) {
        const unsigned short* As = (ch < 4) ? meanbf : xinbf;
        const int kb = (ch & 3) * 32 + lg * 8;
        short8v ah = (short8v){0, 0, 0, 0, 0, 0, 0, 0};
        if (g < n) ah = *(const short8v*)(As + (size_t)g * FEAT + kb);
        #pragma unroll
        for (int ct = 0; ct < NCT; ++ct) {
            int cl = ct * 16 + l15;
            int db = (cl * 512 + ch * 64 + lg * 16) ^ ((cl & 7) << 4);
            short8v bh = *(const short8v*)((const char*)Bh + db);
            short8v bl = *(const short8v*)((const char*)Bl + db);
            acc[ct] = __builtin_amdgcn_mfma_f32_16x16x32_bf16(ah, bh, acc[ct], 0, 0, 0);
            acc[ct] = __builtin_amdgcn_mfma_f32_16x16x32_bf16(ah, bl, acc[ct], 0, 0, 0);
        }
    }

    float t[NCT][4];
    #pragma unroll
    for (int ct = 0; ct < NCT; ++ct) {
        float b = bias[ct * 16 + l15];
        #pragma unroll
        for (int q = 0; q < 4; ++q) {
            float v = acc[ct][q] + b;
            t[ct][q] = (v > 0.f) ? v : expm1f(v);
        }
    }
    if (LSM) {
        #pragma unroll
        for (int q = 0; q < 4; ++q) {
            float m = t[0][q];
            #pragma unroll
            for (int ct = 1; ct < NCT; ++ct) m = fmaxf(m, t[ct][q]);
            #pragma unroll
            for (int s = 1; s < 16; s <<= 1) m = fmaxf(m, __shfl_xor(m, s, 64));
            float sum = 0.f;
            #pragma unroll
            for (int ct = 0; ct < NCT; ++ct) sum += expf(t[ct][q] - m);
            #pragma unroll
            for (int s = 1; s < 16; s <<= 1) sum += __shfl_xor(sum, s, 64);
            float ls = m + logf(sum);
            #pragma unroll
            for (int ct = 0; ct < NCT; ++ct) t[ct][q] -= ls;
        }
    }
    #pragma unroll
    for (int ct = 0; ct < NCT; ++ct) {
        int col = ct * 16 + l15;
        #pragma unroll
        for (int q = 0; q < 4; ++q) {
            int grow = row0 + lg * 4 + q;
            if (grow < n) {
                if (WBF) outbf[(size_t)grow * DOUT + col] = f2bf(t[ct][q]);
                if (WF8) outf8[(size_t)grow * DOUT + col] = f2fp8(t[ct][q]);
                if (!WBF && !WF8) outf[(size_t)grow * DOUT + col] = t[ct][q];
            }
        }
    }
}

extern "C" void kernel_launch(void* const* d_in, const int* in_sizes, int n_in,
                              void* d_out, int out_size, void* d_ws, size_t ws_size,
                              hipStream_t stream) {
    const float* x   = (const float*)d_in[0];
    const float* W1l = (const float*)d_in[1];
    const float* W1r = (const float*)d_in[2];
    const float* b1  = (const float*)d_in[3];
    const float* W2l = (const float*)d_in[4];
    const float* W2r = (const float*)d_in[5];
    const float* b2  = (const float*)d_in[6];
    const float* W3l = (const float*)d_in[7];
    const float* W3r = (const float*)d_in[8];
    const float* b3  = (const float*)d_in[9];
    const int*   src = (const int*)d_in[10];
    const int*   dst = (const int*)d_in[11];

    const int N = in_sizes[0] / FEAT;
    const int E = in_sizes[10];

    const size_t NA = ((size_t)N + 63) & ~(size_t)63;
    const size_t EA = ((size_t)E + 63) & ~(size_t)63;
    const int nb  = (N + 1023) / 1024;
    const int nbk = (N + 511) >> 9;
    const int nch = (E + 8191) / 8192;

    auto alignup = [](char* p) { return (char*)(((uintptr_t)p + 255) & ~(uintptr_t)255); };
    char* p = (char*)d_ws;
    float* invd = (float*)p;                 p += NA * 4;
    int*   offs = (int*)p;                   p += (NA + 64) * 4;
    int*   eidxi = (int*)p;                  p += EA * 4;
    unsigned short* eidx16 = (unsigned short*)eidxi;
    unsigned int* chunkd = (unsigned int*)p; p += (size_t)nch * 8192 * 4;
    int*   table = (int*)p;                  p += (size_t)nch * (nbk + 1) * 4;
    p = alignup(p);
    int*   deg  = (int*)p;                   p += NA * 4;
    int*   cur  = (int*)p;                   p += NA * 4;
    int*   bsum = (int*)p;                   p += 256 * 4;
    int*   bpre = (int*)p;                   p += 256 * 4;
    p = alignup(p);
    unsigned short* WTh1 = (unsigned short*)p; p += 128 * 256 * 2;
    unsigned short* WTl1 = (unsigned short*)p; p += 128 * 256 * 2;
    unsigned short* WTh2 = (unsigned short*)p; p += 128 * 256 * 2;
    unsigned short* WTl2 = (unsigned short*)p; p += 128 * 256 * 2;
    unsigned short* WTh3 = (unsigned short*)p; p += 64 * 256 * 2;
    unsigned short* WTl3 = (unsigned short*)p; p += 64 * 256 * 2;
    p = alignup(p);
    unsigned short* mbf = (unsigned short*)p;  p += NA * FEAT * 2;
    unsigned short* bfA = (unsigned short*)p;  p += NA * FEAT * 2;
    unsigned short* bfB = (unsigned short*)p;  p += NA * FEAT * 2;
    unsigned char*  f8X = (unsigned char*)p;   p += NA * FEAT;
    float* outp = (float*)d_out;

    const int gblocks = (N + 3) / 4;
    const int dblocks = (N + 255) / 256;
    const int total4  = N * FEAT / 4;

    if (N <= 65536) {
        const int pblocks = 80 + (total4 + 1023) / 1024;
        bucket_prep_kernel<<<nch + pblocks, 1024, 0, stream>>>(
            src, dst, chunkd, table, E, nbk, nch,
            W1l, W1r, W2l, W2r, W3l, W3r,
            WTh1, WTl1, WTh2, WTl2, WTh3, WTl3,
            x, bfA, f8X, total4);
        fillsort_kernel<<<nbk, 1024, 0, stream>>>(chunkd, table, offs, invd, eidx16, N, nch, nbk, E);

        gather_f8_kernel<unsigned short><<<gblocks, 256, 0, stream>>>(f8X, offs, eidx16, invd, mbf, N);
        dense_mfma<128, true, true, false><<<dblocks, 1024, 0, stream>>>(mbf, bfA, WTh1, WTl1, b1, nullptr, bfB, f8X, N);

        gather_f8_kernel<unsigned short><<<gblocks, 256, 0, stream>>>(f8X, offs, eidx16, invd, mbf, N);
        dense_mfma<128, true, true, false><<<dblocks, 1024, 0, stream>>>(mbf, bfB, WTh2, WTl2, b2, nullptr, bfA, f8X, N);

        gather_f8_kernel<unsigned short><<<gblocks, 256, 0, stream>>>(f8X, offs, eidx16, invd, mbf, N);
        dense_mfma<64, false, false, true><<<dblocks, 1024, 0, stream>>>(mbf, bfA, WTh3, WTl3, b3, outp, nullptr, nullptr, N);
    } else {
        hipMemsetAsync(deg, 0, (size_t)N * 4, stream);
        deg_kernel<<<(E + 255) / 256, 256, 0, stream>>>(dst, deg, E);
        blockred_kernel<<<nb, 256, 0, stream>>>(deg, bsum, N);
        scanb_kernel<<<1, 256, 0, stream>>>(bsum, bpre, nb);
        scanfill_kernel<<<nb, 256, 0, stream>>>(deg, bpre, offs, cur, invd, N, E);
        const int rsize   = (N + 7) / 8;
        const int fblocks = ((E + FCH - 1) / FCH) * 8;
        fill_xcd_kernel<<<fblocks, 256, 0, stream>>>(src, dst, cur, eidxi, E, rsize);
        prep_kernel<<<320 + (total4 + 255) / 256, 256, 0, stream>>>(
            W1l, W1r, W2l, W2r, W3l, W3r, WTh1, WTl1, WTh2, WTl2, WTh3, WTl3,
            x, bfA, f8X, total4);

        gather_f8_kernel<int><<<gblocks, 256, 0, stream>>>(f8X, offs, eidxi, invd, mbf, N);
        dense_mfma<128, true, true, false><<<dblocks, 1024, 0, stream>>>(mbf, bfA, WTh1, WTl1, b1, nullptr, bfB, f8X, N);

        gather_f8_kernel<int><<<gblocks, 256, 0, stream>>>(f8X, offs, eidxi, invd, mbf, N);
        dense_mfma<128, true, true, false><<<dblocks, 1024, 0, stream>>>(mbf, bfB, WTh2, WTl2, b2, nullptr, bfA, f8X, N);

        gather_f8_kernel<int><<<gblocks, 256, 0, stream>>>(f8X, offs, eidxi, invd, mbf, N);
        dense_mfma<64, false, false, true><<<dblocks, 1024, 0, stream>>>(mbf, bfA, WTh3, WTl3, b3, outp, nullptr, nullptr, N);
    }
}

// Round 20
// 152.566 us; speedup vs baseline: 1.1297x; 1.1297x over previous
//
#include <hip/hip_runtime.h>
#include <math.h>

constexpr int FEAT = 128;   // DIN == DH == 128

typedef __attribute__((ext_vector_type(8))) short short8v;   // 8 bf16 raw / 16 B
typedef __attribute__((ext_vector_type(4))) float f32x4;
typedef __attribute__((ext_vector_type(2))) float f32x2;
typedef __attribute__((ext_vector_type(4))) int   int4v;

// ---- fp32 -> bf16 (RNE) / fp8 helpers ----
__device__ inline unsigned short f2bf(float f) {
    unsigned int u = __float_as_uint(f);
    u += 0x7fffu + ((u >> 16) & 1u);
    return (unsigned short)(u >> 16);
}
__device__ inline float bf2f(unsigned short h) {
    return __uint_as_float(((unsigned int)h) << 16);
}
__device__ inline unsigned char f2fp8(float f) {
    int r = __builtin_amdgcn_cvt_pk_fp8_f32(f, 0.f, 0, false);
    return (unsigned char)(r & 0xff);
}

// ================= fused CSR bucket phase 1 + weight/x prep =================
__global__ __launch_bounds__(1024) void bucket_prep_kernel(
    const int* __restrict__ src, const int* __restrict__ dst,
    unsigned int* __restrict__ chunkdata, int* __restrict__ table,
    int E, int nbk, int nch,
    const float* __restrict__ W1l, const float* __restrict__ W1r,
    const float* __restrict__ W2l, const float* __restrict__ W2r,
    const float* __restrict__ W3l, const float* __restrict__ W3r,
    unsigned short* __restrict__ WTh1, unsigned short* __restrict__ WTl1,
    unsigned short* __restrict__ WTh2, unsigned short* __restrict__ WTl2,
    unsigned short* __restrict__ WTh3, unsigned short* __restrict__ WTl3,
    const float* __restrict__ x, unsigned short* __restrict__ xbf,
    unsigned char* __restrict__ xf8, int total4)
{
    __shared__ int cnt[128];
    __shared__ int part[128];
    __shared__ int sbase[128];
    __shared__ unsigned int sbuf[8192];
    const int t = threadIdx.x;
    const int blk = blockIdx.x;

    if (blk >= nch) {
        int b = blk - nch;
        if (b < 80) {
            const float *Wl, *Wr;
            unsigned short *WTh, *WTl;
            int dout, idx;
            if (b < 32)      { Wl = W1l; Wr = W1r; WTh = WTh1; WTl = WTl1; dout = 128; idx = b * 1024 + t; }
            else if (b < 64) { Wl = W2l; Wr = W2r; WTh = WTh2; WTl = WTl2; dout = 128; idx = (b - 32) * 1024 + t; }
            else             { Wl = W3l; Wr = W3r; WTh = WTh3; WTl = WTl3; dout = 64;  idx = (b - 64) * 1024 + t; }
            if (idx < dout * 256) {
                int c = idx >> 8;
                int k = idx & 255;
                float v = (k < 128) ? Wl[(size_t)k * dout + c] : Wr[(size_t)(k - 128) * dout + c];
                unsigned short h = f2bf(v);
                WTh[(size_t)c * 256 + k] = h;
                WTl[(size_t)c * 256 + k] = f2bf(v - bf2f(h));
            }
        } else {
            int i = (b - 80) * 1024 + t;
            if (i < total4) {
                float4 v = *(const float4*)(x + (size_t)i * 4);
                ushort4 h;
                h.x = f2bf(v.x); h.y = f2bf(v.y); h.z = f2bf(v.z); h.w = f2bf(v.w);
                *(ushort4*)(xbf + (size_t)i * 4) = h;
                uchar4 c;
                c.x = f2fp8(v.x); c.y = f2fp8(v.y); c.z = f2fp8(v.z); c.w = f2fp8(v.w);
                *(uchar4*)(xf8 + (size_t)i * 4) = c;
            }
        }
        return;
    }

    const int c = blk;
    const int e0 = c * 8192;

    if (t < 128) cnt[t] = 0;
    __syncthreads();

    unsigned int word[8];
    int bkt[8], rnk[8];
    #pragma unroll
    for (int it = 0; it < 2; ++it) {
        int e = e0 + it * 4096 + t * 4;
        int4 d4 = make_int4(0, 0, 0, 0), s4 = d4;
        if (e + 3 < E) {
            d4 = *(const int4*)(dst + e);
            s4 = *(const int4*)(src + e);
        } else {
            if (e + 0 < E) { d4.x = dst[e + 0]; s4.x = src[e + 0]; } else d4.x = -1;
            if (e + 1 < E) { d4.y = dst[e + 1]; s4.y = src[e + 1]; } else d4.y = -1;
            if (e + 2 < E) { d4.z = dst[e + 2]; s4.z = src[e + 2]; } else d4.z = -1;
            if (e + 3 < E) { d4.w = dst[e + 3]; s4.w = src[e + 3]; } else d4.w = -1;
        }
        int dd[4] = {d4.x, d4.y, d4.z, d4.w};
        int ss[4] = {s4.x, s4.y, s4.z, s4.w};
        #pragma unroll
        for (int q = 0; q < 4; ++q) {
            int i = it * 4 + q;
            int d = dd[q];
            if (d >= 0) {
                bkt[i]  = d >> 9;
                rnk[i]  = atomicAdd(&cnt[bkt[i]], 1);
                word[i] = (unsigned int)ss[q] | ((unsigned int)(d & 511) << 16);
            } else bkt[i] = -1;
        }
    }
    __syncthreads();

    if (t < 128) part[t] = cnt[t];
    __syncthreads();
    for (int s = 1; s < 128; s <<= 1) {
        int v = (t >= s && t < 128) ? part[t - s] : 0;
        __syncthreads();
        if (t < 128) part[t] += v;
        __syncthreads();
    }
    if (t < 128) sbase[t] = part[t] - cnt[t];
    __syncthreads();

    if (t <= nbk) table[(size_t)c * (nbk + 1) + t] = sbase[t];

    #pragma unroll
    for (int i = 0; i < 8; ++i)
        if (bkt[i] >= 0) sbuf[sbase[bkt[i]] + rnk[i]] = word[i];
    __syncthreads();

    const int total = part[127];
    for (int i = t; i < total; i += 1024)
        chunkdata[(size_t)c * 8192 + i] = sbuf[i];
}

// Phase 2: per-bucket two-pass counting sort -> offs/invd + ushort eidx flush.
constexpr int P2CAP = 10240;
__global__ __launch_bounds__(1024) void fillsort_kernel(const unsigned int* __restrict__ chunkdata,
                                                        const int* __restrict__ table,
                                                        int* __restrict__ offs,
                                                        float* __restrict__ invd,
                                                        unsigned short* __restrict__ eidx,
                                                        int n, int nch, int nbk, int E) {
    __shared__ int cnt[512];
    __shared__ int lcur[512];
    __shared__ int part[512];
    __shared__ int redb[16];
    __shared__ int lbuf[P2CAP];
    const int b  = blockIdx.x;
    const int t  = threadIdx.x;
    const int lo = b << 9;

    int partial = 0;
    for (int c = t; c < nch; c += 1024) partial += table[(size_t)c * (nbk + 1) + b];
    #pragma unroll
    for (int off = 32; off > 0; off >>= 1) partial += __shfl_down(partial, off, 64);
    if ((t & 63) == 0) redb[t >> 6] = partial;
    for (int i = t; i < 512; i += 1024) cnt[i] = 0;
    __syncthreads();
    int base = 0;
    #pragma unroll
    for (int i = 0; i < 16; ++i) base += redb[i];

    const int w    = t >> 6;
    const int lane = t & 63;
    for (int c = w; c < nch; c += 16) {
        int o0 = table[(size_t)c * (nbk + 1) + b];
        int o1 = table[(size_t)c * (nbk + 1) + b + 1];
        for (int i = o0 + lane; i < o1; i += 64)
            atomicAdd(&cnt[(chunkdata[(size_t)c * 8192 + i] >> 16) & 511], 1);
    }
    __syncthreads();

    int v = (t < 512) ? cnt[t] : 0;
    if (t < 512) part[t] = v;
    __syncthreads();
    for (int s = 1; s < 512; s <<= 1) {
        int u = (t >= s && t < 512) ? part[t - s] : 0;
        __syncthreads();
        if (t < 512) part[t] += u;
        __syncthreads();
    }
    const int total = part[511];
    if (t < 512) {
        int ex = part[t] - v;
        lcur[t] = ex;
        int idx = lo + t;
        if (idx < n) {
            offs[idx] = base + ex;
            invd[idx] = 1.0f / fmaxf((float)v, 1.0f);
        }
    }
    if (b == nbk - 1 && t == 0) offs[n] = E;
    __syncthreads();

    for (int c = w; c < nch; c += 16) {
        int o0 = table[(size_t)c * (nbk + 1) + b];
        int o1 = table[(size_t)c * (nbk + 1) + b + 1];
        for (int i = o0 + lane; i < o1; i += 64) {
            unsigned int wd = chunkdata[(size_t)c * 8192 + i];
            int s = wd & 0xffff;
            int p = atomicAdd(&lcur[(wd >> 16) & 511], 1);
            if (p < P2CAP) lbuf[p] = s;
            else           eidx[base + p] = (unsigned short)s;
        }
    }
    __syncthreads();

    const int m = min(total, P2CAP);
    for (int i = t; i < m; i += 1024) eidx[base + i] = (unsigned short)lbuf[i];
}

// ================= CSR build fallback (N > 65536) =================
__global__ void deg_kernel(const int* __restrict__ dst, int* __restrict__ degi, int E) {
    int e = blockIdx.x * 256 + threadIdx.x;
    if (e < E) atomicAdd(&degi[__builtin_nontemporal_load(dst + e)], 1);
}
__global__ __launch_bounds__(256) void blockred_kernel(const int* __restrict__ deg,
                                                       int* __restrict__ bsum, int n) {
    __shared__ int red[256];
    int base = blockIdx.x * 1024 + threadIdx.x * 4;
    int s = 0;
    if (base + 3 < n) {
        int4 v = *(const int4*)(deg + base);
        s = v.x + v.y + v.z + v.w;
    } else {
        for (int i = 0; i < 4; ++i) if (base + i < n) s += deg[base + i];
    }
    red[threadIdx.x] = s;
    __syncthreads();
    for (int st = 128; st > 0; st >>= 1) {
        if (threadIdx.x < st) red[threadIdx.x] += red[threadIdx.x + st];
        __syncthreads();
    }
    if (threadIdx.x == 0) bsum[blockIdx.x] = red[0];
}
__global__ __launch_bounds__(256) void scanb_kernel(const int* __restrict__ bsum,
                                                    int* __restrict__ bpre, int nb) {
    __shared__ int part[256];
    int t = threadIdx.x;
    int v = (t < nb) ? bsum[t] : 0;
    part[t] = v;
    __syncthreads();
    for (int s = 1; s < 256; s <<= 1) {
        int u = (t >= s) ? part[t - s] : 0;
        __syncthreads();
        part[t] += u;
        __syncthreads();
    }
    if (t < nb) bpre[t] = part[t] - v;
}
__global__ __launch_bounds__(256) void scanfill_kernel(const int* __restrict__ deg,
                                                       const int* __restrict__ bpre,
                                                       int* __restrict__ offs,
                                                       int* __restrict__ cur,
                                                       float* __restrict__ invd,
                                                       int n, int E) {
    __shared__ int part[256];
    int t = threadIdx.x;
    int base = blockIdx.x * 1024 + t * 4;
    int d[4];
    int s = 0;
    #pragma unroll
    for (int i = 0; i < 4; ++i) {
        d[i] = (base + i < n) ? deg[base + i] : 0;
        s += d[i];
    }
    part[t] = s;
    __syncthreads();
    for (int st = 1; st < 256; st <<= 1) {
        int u = (t >= st) ? part[t - st] : 0;
        __syncthreads();
        part[t] += u;
        __syncthreads();
    }
    int pre = bpre[blockIdx.x] + part[t] - s;
    #pragma unroll
    for (int i = 0; i < 4; ++i) {
        int idx = base + i;
        if (idx < n) {
            offs[idx] = pre;
            cur[idx]  = pre;
            invd[idx] = 1.0f / fmaxf((float)d[i], 1.0f);
            pre += d[i];
        }
    }
    if (blockIdx.x == 0 && t == 0) offs[n] = E;
}
constexpr int FCH = 4096;
__global__ __launch_bounds__(256) void fill_xcd_kernel(const int* __restrict__ src,
                                                       const int* __restrict__ dst,
                                                       int* __restrict__ cur,
                                                       int* __restrict__ eidx,
                                                       int E, int rsize) {
    const int p     = blockIdx.x & 7;
    const int chunk = blockIdx.x >> 3;
    const int lo = p * rsize;
    const int hi = lo + rsize;
    #pragma unroll
    for (int it = 0; it < 4; ++it) {
        int e = chunk * FCH + (it * 256 + threadIdx.x) * 4;
        if (e + 3 < E) {
            int4v d4 = __builtin_nontemporal_load((const int4v*)(dst + e));
            #pragma unroll
            for (int q = 0; q < 4; ++q) {
                int d = d4[q];
                if (d >= lo && d < hi) {
                    int pos = atomicAdd(&cur[d], 1);
                    eidx[pos] = __builtin_nontemporal_load(src + e + q);
                }
            }
        } else {
            for (int q = 0; e + q < E && q < 4; ++q) {
                int d = dst[e + q];
                if (d >= lo && d < hi) {
                    int pos = atomicAdd(&cur[d], 1);
                    eidx[pos] = src[e + q];
                }
            }
        }
    }
}
__global__ __launch_bounds__(256) void prep_kernel(
    const float* __restrict__ W1l, const float* __restrict__ W1r,
    const float* __restrict__ W2l, const float* __restrict__ W2r,
    const float* __restrict__ W3l, const float* __restrict__ W3r,
    unsigned short* __restrict__ WTh1, unsigned short* __restrict__ WTl1,
    unsigned short* __restrict__ WTh2, unsigned short* __restrict__ WTl2,
    unsigned short* __restrict__ WTh3, unsigned short* __restrict__ WTl3,
    const float* __restrict__ x, unsigned short* __restrict__ xbf,
    unsigned char* __restrict__ xf8, int total4)
{
    const int b = blockIdx.x;
    if (b < 320) {
        const float *Wl, *Wr;
        unsigned short *WTh, *WTl;
        int dout, idx;
        if (b < 128)      { Wl = W1l; Wr = W1r; WTh = WTh1; WTl = WTl1; dout = 128; idx = b * 256 + threadIdx.x; }
        else if (b < 256) { Wl = W2l; Wr = W2r; WTh = WTh2; WTl = WTl2; dout = 128; idx = (b - 128) * 256 + threadIdx.x; }
        else              { Wl = W3l; Wr = W3r; WTh = WTh3; WTl = WTl3; dout = 64;  idx = (b - 256) * 256 + threadIdx.x; }
        if (idx < dout * 256) {
            int c = idx >> 8;
            int k = idx & 255;
            float v = (k < 128) ? Wl[(size_t)k * dout + c] : Wr[(size_t)(k - 128) * dout + c];
            unsigned short h = f2bf(v);
            WTh[(size_t)c * 256 + k] = h;
            WTl[(size_t)c * 256 + k] = f2bf(v - bf2f(h));
        }
    } else {
        int i = (b - 320) * 256 + threadIdx.x;
        if (i < total4) {
            float4 v = *(const float4*)(x + (size_t)i * 4);
            ushort4 h;
            h.x = f2bf(v.x); h.y = f2bf(v.y); h.z = f2bf(v.z); h.w = f2bf(v.w);
            *(ushort4*)(xbf + (size_t)i * 4) = h;
            uchar4 c;
            c.x = f2fp8(v.x); c.y = f2fp8(v.y); c.z = f2fp8(v.z); c.w = f2fp8(v.w);
            *(uchar4*)(xf8 + (size_t)i * 4) = c;
        }
    }
}

// ================= gather mean from fp8 feats -> bf16 mean =================
// (round-18 configuration: best measured) 16-lane groups x 8-B loads, LDS-
// staged coalesced index prefetch (exec-mask-safe), 16 rows in flight/wave.
template <typename IT>
__global__ __launch_bounds__(256) void gather_f8_kernel(const unsigned char* __restrict__ featf8,
                                                        const int* __restrict__ offs,
                                                        const IT* __restrict__ eidx,
                                                        const float* __restrict__ invd,
                                                        unsigned short* __restrict__ aggbf, int n) {
    __shared__ int sidx[4][64];
    const int widx = threadIdx.x >> 6;
    int node = blockIdx.x * 4 + widx;
    if (node >= n) return;
    const int l   = threadIdx.x & 63;
    const int grp = l >> 4;
    const int li  = l & 15;
    const int c8  = li * 8;
    const int beg = offs[node], end = offs[node + 1];
    const int deg = end - beg;

    // one coalesced index prefetch into this wave's private LDS slice
    if (l < deg) sidx[widx][l] = (int)eidx[beg + l];

    float acc[8];
    #pragma unroll
    for (int q = 0; q < 8; ++q) acc[q] = 0.f;

    const int m = min(deg, 64);
    int k = grp;
    // main loop: 4 rows deep per group -> 16 feature loads in flight per wave
    for (; k + 12 < m; k += 16) {
        int s0 = sidx[widx][k];
        int s1 = sidx[widx][k + 4];
        int s2 = sidx[widx][k + 8];
        int s3 = sidx[widx][k + 12];
        uint2 v0 = *(const uint2*)(featf8 + (size_t)s0 * FEAT + c8);
        uint2 v1 = *(const uint2*)(featf8 + (size_t)s1 * FEAT + c8);
        uint2 v2 = *(const uint2*)(featf8 + (size_t)s2 * FEAT + c8);
        uint2 v3 = *(const uint2*)(featf8 + (size_t)s3 * FEAT + c8);
        f32x2 p;
        p = __builtin_amdgcn_cvt_pk_f32_fp8(v0.x, false); acc[0] += p.x; acc[1] += p.y;
        p = __builtin_amdgcn_cvt_pk_f32_fp8(v0.x, true);  acc[2] += p.x; acc[3] += p.y;
        p = __builtin_amdgcn_cvt_pk_f32_fp8(v0.y, false); acc[4] += p.x; acc[5] += p.y;
        p = __builtin_amdgcn_cvt_pk_f32_fp8(v0.y, true);  acc[6] += p.x; acc[7] += p.y;
        p = __builtin_amdgcn_cvt_pk_f32_fp8(v1.x, false); acc[0] += p.x; acc[1] += p.y;
        p = __builtin_amdgcn_cvt_pk_f32_fp8(v1.x, true);  acc[2] += p.x; acc[3] += p.y;
        p = __builtin_amdgcn_cvt_pk_f32_fp8(v1.y, false); acc[4] += p.x; acc[5] += p.y;
        p = __builtin_amdgcn_cvt_pk_f32_fp8(v1.y, true);  acc[6] += p.x; acc[7] += p.y;
        p = __builtin_amdgcn_cvt_pk_f32_fp8(v2.x, false); acc[0] += p.x; acc[1] += p.y;
        p = __builtin_amdgcn_cvt_pk_f32_fp8(v2.x, true);  acc[2] += p.x; acc[3] += p.y;
        p = __builtin_amdgcn_cvt_pk_f32_fp8(v2.y, false); acc[4] += p.x; acc[5] += p.y;
        p = __builtin_amdgcn_cvt_pk_f32_fp8(v2.y, true);  acc[6] += p.x; acc[7] += p.y;
        p = __builtin_amdgcn_cvt_pk_f32_fp8(v3.x, false); acc[0] += p.x; acc[1] += p.y;
        p = __builtin_amdgcn_cvt_pk_f32_fp8(v3.x, true);  acc[2] += p.x; acc[3] += p.y;
        p = __builtin_amdgcn_cvt_pk_f32_fp8(v3.y, false); acc[4] += p.x; acc[5] += p.y;
        p = __builtin_amdgcn_cvt_pk_f32_fp8(v3.y, true);  acc[6] += p.x; acc[7] += p.y;
    }
    for (; k < m; k += 4) {
        int s0 = sidx[widx][k];
        uint2 v0 = *(const uint2*)(featf8 + (size_t)s0 * FEAT + c8);
        f32x2 p;
        p = __builtin_amdgcn_cvt_pk_f32_fp8(v0.x, false); acc[0] += p.x; acc[1] += p.y;
        p = __builtin_amdgcn_cvt_pk_f32_fp8(v0.x, true);  acc[2] += p.x; acc[3] += p.y;
        p = __builtin_amdgcn_cvt_pk_f32_fp8(v0.y, false); acc[4] += p.x; acc[5] += p.y;
        p = __builtin_amdgcn_cvt_pk_f32_fp8(v0.y, true);  acc[6] += p.x; acc[7] += p.y;
    }
    // rare tail: deg > 64 (direct loads, still correct)
    for (int j = beg + 64 + grp; j < end; j += 4) {
        int s0 = (int)eidx[j];
        uint2 v0 = *(const uint2*)(featf8 + (size_t)s0 * FEAT + c8);
        f32x2 p;
        p = __builtin_amdgcn_cvt_pk_f32_fp8(v0.x, false); acc[0] += p.x; acc[1] += p.y;
        p = __builtin_amdgcn_cvt_pk_f32_fp8(v0.x, true);  acc[2] += p.x; acc[3] += p.y;
        p = __builtin_amdgcn_cvt_pk_f32_fp8(v0.y, false); acc[4] += p.x; acc[5] += p.y;
        p = __builtin_amdgcn_cvt_pk_f32_fp8(v0.y, true);  acc[6] += p.x; acc[7] += p.y;
    }

    // reduce across the 4 groups (wave-convergent point)
    #pragma unroll
    for (int off = 16; off < 64; off <<= 1)
        #pragma unroll
        for (int q = 0; q < 8; ++q)
            acc[q] += __shfl_xor(acc[q], off, 64);

    if (grp == 0) {
        float sc = invd[node];
        unsigned short o[8];
        #pragma unroll
        for (int q = 0; q < 8; ++q) o[q] = f2bf(acc[q] * sc);
        *(short8v*)(aggbf + (size_t)node * FEAT + c8) = *(short8v*)o;
    }
}

// ================= MFMA dense, LDS-resident B (ALL DOUT cols) =================
template <int DOUT, bool WBF, bool WF8, bool LSM>
__global__ __launch_bounds__(1024, 4) void dense_mfma(
    const unsigned short* __restrict__ meanbf, const unsigned short* __restrict__ xinbf,
    const unsigned short* __restrict__ WTh, const unsigned short* __restrict__ WTl,
    const float* __restrict__ bias,
    float* outf, unsigned short* outbf, unsigned char* outf8, int n)
{
    constexpr int NCT = DOUT / 16;
    __shared__ unsigned short Bh[DOUT * 256];
    __shared__ unsigned short Bl[DOUT * 256];
    const int tid = threadIdx.x;

    #pragma unroll
    for (int it = 0; it < DOUT / 32; ++it) {
        int o  = (tid + it * 1024) * 8;
        int cl = o >> 8;
        int k  = o & 255;
        size_t gsrc = (size_t)cl * 256 + k;
        int db = (o * 2) ^ ((cl & 7) << 4);
        *(short8v*)((char*)Bh + db) = *(const short8v*)(WTh + gsrc);
        *(short8v*)((char*)Bl + db) = *(const short8v*)(WTl + gsrc);
    }
    __syncthreads();

    const int l    = tid & 63;
    const int w    = tid >> 6;
    const int l15  = l & 15;
    const int lg   = l >> 4;
    const int row0 = blockIdx.x * 256 + w * 16;
    if (row0 >= n) return;
    const int g = row0 + l15;

    f32x4 acc[NCT];
    #pragma unroll
    for (int ct = 0; ct < NCT; ++ct) acc[ct] = (f32x4){0.f, 0.f, 0.f, 0.f};

    #pragma unroll
    for (int ch = 0; ch < 8; ++ch) {
        const unsigned short* As = (ch < 4) ? meanbf : xinbf;
        const int kb = (ch & 3) * 32 + lg * 8;
        short8v ah = (short8v){0, 0, 0, 0, 0, 0, 0, 0};
        if (g < n) ah = *(const short8v*)(As + (size_t)g * FEAT + kb);
        #pragma unroll
        for (int ct = 0; ct < NCT; ++ct) {
            int cl = ct * 16 + l15;
            int db = (cl * 512 + ch * 64 + lg * 16) ^ ((cl & 7) << 4);
            short8v bh = *(const short8v*)((const char*)Bh + db);
            short8v bl = *(const short8v*)((const char*)Bl + db);
            acc[ct] = __builtin_amdgcn_mfma_f32_16x16x32_bf16(ah, bh, acc[ct], 0, 0, 0);
            acc[ct] = __builtin_amdgcn_mfma_f32_16x16x32_bf16(ah, bl, acc[ct], 0, 0, 0);
        }
    }

    float t[NCT][4];
    #pragma unroll
    for (int ct = 0; ct < NCT; ++ct) {
        float b = bias[ct * 16 + l15];
        #pragma unroll
        for (int q = 0; q < 4; ++q) {
            float v = acc[ct][q] + b;
            t[ct][q] = (v > 0.f) ? v : expm1f(v);
        }
    }
    if (LSM) {
        #pragma unroll
        for (int q = 0; q < 4; ++q) {
            float m = t[0][q];
            #pragma unroll
            for (int ct = 1; ct < NCT; ++ct) m = fmaxf(m, t[ct][q]);
            #pragma unroll
            for (int s = 1; s < 16; s <<= 1) m = fmaxf(m, __shfl_xor(m, s, 64));
            float sum = 0.f;
            #pragma unroll
            for (int ct = 0; ct < NCT; ++ct) sum += expf(t[ct][q] - m);
            #pragma unroll
            for (int s = 1; s < 16; s <<= 1) sum += __shfl_xor(sum, s, 64);
            float ls = m + logf(sum);
            #pragma unroll
            for (int ct = 0; ct < NCT; ++ct) t[ct][q] -= ls;
        }
    }
    #pragma unroll
    for (int ct = 0; ct < NCT; ++ct) {
        int col = ct * 16 + l15;
        #pragma unroll
        for (int q = 0; q < 4; ++q) {
            int grow = row0 + lg * 4 + q;
            if (grow < n) {
                if (WBF) outbf[(size_t)grow * DOUT + col] = f2bf(t[ct][q]);
                if (WF8) outf8[(size_t)grow * DOUT + col] = f2fp8(t[ct][q]);
                if (!WBF && !WF8) outf[(size_t)grow * DOUT + col] = t[ct][q];
            }
        }
    }
}

extern "C" void kernel_launch(void* const* d_in, const int* in_sizes, int n_in,
                              void* d_out, int out_size, void* d_ws, size_t ws_size,
                              hipStream_t stream) {
    const float* x   = (const float*)d_in[0];
    const float* W1l = (const float*)d_in[1];
    const float* W1r = (const float*)d_in[2];
    const float* b1  = (const float*)d_in[3];
    const float* W2l = (const float*)d_in[4];
    const float* W2r = (const float*)d_in[5];
    const float* b2  = (const float*)d_in[6];
    const float* W3l = (const float*)d_in[7];
    const float* W3r = (const float*)d_in[8];
    const float* b3  = (const float*)d_in[9];
    const int*   src = (const int*)d_in[10];
    const int*   dst = (const int*)d_in[11];

    const int N = in_sizes[0] / FEAT;
    const int E = in_sizes[10];

    const size_t NA = ((size_t)N + 63) & ~(size_t)63;
    const size_t EA = ((size_t)E + 63) & ~(size_t)63;
    const int nb  = (N + 1023) / 1024;
    const int nbk = (N + 511) >> 9;
    const int nch = (E + 8191) / 8192;

    auto alignup = [](char* p) { return (char*)(((uintptr_t)p + 255) & ~(uintptr_t)255); };
    char* p = (char*)d_ws;
    float* invd = (float*)p;                 p += NA * 4;
    int*   offs = (int*)p;                   p += (NA + 64) * 4;
    int*   eidxi = (int*)p;                  p += EA * 4;
    unsigned short* eidx16 = (unsigned short*)eidxi;
    unsigned int* chunkd = (unsigned int*)p; p += (size_t)nch * 8192 * 4;
    int*   table = (int*)p;                  p += (size_t)nch * (nbk + 1) * 4;
    p = alignup(p);
    int*   deg  = (int*)p;                   p += NA * 4;
    int*   cur  = (int*)p;                   p += NA * 4;
    int*   bsum = (int*)p;                   p += 256 * 4;
    int*   bpre = (int*)p;                   p += 256 * 4;
    p = alignup(p);
    unsigned short* WTh1 = (unsigned short*)p; p += 128 * 256 * 2;
    unsigned short* WTl1 = (unsigned short*)p; p += 128 * 256 * 2;
    unsigned short* WTh2 = (unsigned short*)p; p += 128 * 256 * 2;
    unsigned short* WTl2 = (unsigned short*)p; p += 128 * 256 * 2;
    unsigned short* WTh3 = (unsigned short*)p; p += 64 * 256 * 2;
    unsigned short* WTl3 = (unsigned short*)p; p += 64 * 256 * 2;
    p = alignup(p);
    unsigned short* mbf = (unsigned short*)p;  p += NA * FEAT * 2;
    unsigned short* bfA = (unsigned short*)p;  p += NA * FEAT * 2;
    unsigned short* bfB = (unsigned short*)p;  p += NA * FEAT * 2;
    unsigned char*  f8X = (unsigned char*)p;   p += NA * FEAT;
    float* outp = (float*)d_out;

    const int gblocks = (N + 3) / 4;
    const int dblocks = (N + 255) / 256;
    const int total4  = N * FEAT / 4;

    if (N <= 65536) {
        const int pblocks = 80 + (total4 + 1023) / 1024;
        bucket_prep_kernel<<<nch + pblocks, 1024, 0, stream>>>(
            src, dst, chunkd, table, E, nbk, nch,
            W1l, W1r, W2l, W2r, W3l, W3r,
            WTh1, WTl1, WTh2, WTl2, WTh3, WTl3,
            x, bfA, f8X, total4);
        fillsort_kernel<<<nbk, 1024, 0, stream>>>(chunkd, table, offs, invd, eidx16, N, nch, nbk, E);

        gather_f8_kernel<unsigned short><<<gblocks, 256, 0, stream>>>(f8X, offs, eidx16, invd, mbf, N);
        dense_mfma<128, true, true, false><<<dblocks, 1024, 0, stream>>>(mbf, bfA, WTh1, WTl1, b1, nullptr, bfB, f8X, N);

        gather_f8_kernel<unsigned short><<<gblocks, 256, 0, stream>>>(f8X, offs, eidx16, invd, mbf, N);
        dense_mfma<128, true, true, false><<<dblocks, 1024, 0, stream>>>(mbf, bfB, WTh2, WTl2, b2, nullptr, bfA, f8X, N);

        gather_f8_kernel<unsigned short><<<gblocks, 256, 0, stream>>>(f8X, offs, eidx16, invd, mbf, N);
        dense_mfma<64, false, false, true><<<dblocks, 1024, 0, stream>>>(mbf, bfA, WTh3, WTl3, b3, outp, nullptr, nullptr, N);
    } else {
        hipMemsetAsync(deg, 0, (size_t)N * 4, stream);
        deg_kernel<<<(E + 255) / 256, 256, 0, stream>>>(dst, deg, E);
        blockred_kernel<<<nb, 256, 0, stream>>>(deg, bsum, N);
        scanb_kernel<<<1, 256, 0, stream>>>(bsum, bpre, nb);
        scanfill_kernel<<<nb, 256, 0, stream>>>(deg, bpre, offs, cur, invd, N, E);
        const int rsize   = (N + 7) / 8;
        const int fblocks = ((E + FCH - 1) / FCH) * 8;
        fill_xcd_kernel<<<fblocks, 256, 0, stream>>>(src, dst, cur, eidxi, E, rsize);
        prep_kernel<<<320 + (total4 + 255) / 256, 256, 0, stream>>>(
            W1l, W1r, W2l, W2r, W3l, W3r, WTh1, WTl1, WTh2, WTl2, WTh3, WTl3,
            x, bfA, f8X, total4);

        gather_f8_kernel<int><<<gblocks, 256, 0, stream>>>(f8X, offs, eidxi, invd, mbf, N);
        dense_mfma<128, true, true, false><<<dblocks, 1024, 0, stream>>>(mbf, bfA, WTh1, WTl1, b1, nullptr, bfB, f8X, N);

        gather_f8_kernel<int><<<gblocks, 256, 0, stream>>>(f8X, offs, eidxi, invd, mbf, N);
        dense_mfma<128, true, true, false><<<dblocks, 1024, 0, stream>>>(mbf, bfB, WTh2, WTl2, b2, nullptr, bfA, f8X, N);

        gather_f8_kernel<int><<<gblocks, 256, 0, stream>>>(f8X, offs, eidxi, invd, mbf, N);
        dense_mfma<64, false, false, true><<<dblocks, 1024, 0, stream>>>(mbf, bfA, WTh3, WTl3, b3, outp, nullptr, nullptr, N);
    }
}